// Round 1
// baseline (7168.433 us; speedup 1.0000x reference)
//
#include <hip/hip_runtime.h>
#include <hip/hip_bf16.h>

typedef unsigned int u32;
typedef unsigned short u16;

#define NNODE 100000
#define NVAR  60000
#define NCON  40000
#define NEDGE 500000

// ---- helpers -------------------------------------------------------------
__device__ __forceinline__ float bf2f(u16 u) { return __uint_as_float(((u32)u) << 16); }
__device__ __forceinline__ u16 f2bf(float f) {
  u32 u = __float_as_uint(f);
  u32 r = (u + 0x7fffu + ((u >> 16) & 1u)) >> 16;   // RNE
  return (u16)r;
}
__device__ __forceinline__ float cvlo(u32 p) { return __uint_as_float(p << 16); }
__device__ __forceinline__ float cvhi(u32 p) { return __uint_as_float(p & 0xffff0000u); }
__device__ __forceinline__ float sigmoidf_(float x) {
  return __builtin_amdgcn_rcpf(1.0f + __expf(-x));
}

// ---- node init: var nodes -> x0 rows [mlp(62), v, 1] ---------------------
__global__ __launch_bounds__(256) void k_var_init(
    const float* __restrict__ vf, const int* __restrict__ assoc,
    const float* __restrict__ w1, const float* __restrict__ b1,
    const float* __restrict__ w2, const float* __restrict__ b2,
    u16* __restrict__ x0)
{
  __shared__ float sw2[62 * 62];
  __shared__ float sw1[62], sb1[62], sb2[62];
  for (int i = threadIdx.x; i < 62 * 62; i += 256) sw2[i] = w2[i];
  if (threadIdx.x < 62) {
    sw1[threadIdx.x] = w1[threadIdx.x];
    sb1[threadIdx.x] = b1[threadIdx.x];
    sb2[threadIdx.x] = b2[threadIdx.x];
  }
  __syncthreads();
  int i = blockIdx.x * 256 + threadIdx.x;
  if (i >= NVAR) return;
  float v = vf[i];
  float h[62];
#pragma unroll
  for (int j = 0; j < 62; ++j) h[j] = fmaxf(fmaf(v, sw1[j], sb1[j]), 0.f);
  int r = assoc[i];
  u16* orow = x0 + (size_t)r * 64;
#pragma unroll 1
  for (int d = 0; d < 62; ++d) {
    float acc = sb2[d];
#pragma unroll
    for (int k = 0; k < 62; ++k) acc = fmaf(h[k], sw2[k * 62 + d], acc);
    orow[d] = f2bf(acc);
  }
  orow[62] = f2bf(v);
  orow[63] = 0x3f80;  // 1.0 bf16
}

// ---- node init: con nodes -> x0 rows [mlp(63), c] ------------------------
__global__ __launch_bounds__(256) void k_con_init(
    const float* __restrict__ cf, const int* __restrict__ assoc,
    const float* __restrict__ w1, const float* __restrict__ b1,
    const float* __restrict__ w2, const float* __restrict__ b2,
    u16* __restrict__ x0)
{
  __shared__ float sw2[63 * 63];
  __shared__ float sw1[63], sb1[63], sb2[63];
  for (int i = threadIdx.x; i < 63 * 63; i += 256) sw2[i] = w2[i];
  if (threadIdx.x < 63) {
    sw1[threadIdx.x] = w1[threadIdx.x];
    sb1[threadIdx.x] = b1[threadIdx.x];
    sb2[threadIdx.x] = b2[threadIdx.x];
  }
  __syncthreads();
  int i = blockIdx.x * 256 + threadIdx.x;
  if (i >= NCON) return;
  float c = cf[i];
  float h[63];
#pragma unroll
  for (int j = 0; j < 63; ++j) h[j] = fmaxf(fmaf(c, sw1[j], sb1[j]), 0.f);
  int r = assoc[i];
  u16* orow = x0 + (size_t)r * 64;
#pragma unroll 1
  for (int d = 0; d < 63; ++d) {
    float acc = sb2[d];
#pragma unroll
    for (int k = 0; k < 63; ++k) acc = fmaf(h[k], sw2[k * 63 + d], acc);
    orow[d] = f2bf(acc);
  }
  orow[63] = f2bf(c);
}

// ---- aggr[n][d] = bias[d] (layer 0 pre-fill) -----------------------------
__global__ void k_aggr_init(float4* __restrict__ aggr, const float* __restrict__ bias)
{
  int i = blockIdx.x * 256 + threadIdx.x;   // exactly NNODE*16 threads
  int d = (i & 15) * 4;
  aggr[i] = make_float4(bias[d], bias[d + 1], bias[d + 2], bias[d + 3]);
}

// ---- per-layer edge kernel ----------------------------------------------
// msg = (t==0) ? [xj[:62]@Wc, xj[62], (sigmoid(xj@W1+b1)@w2+b2)*ef[src]]
//              : xj@Wv      ; atomically accumulated into aggr[dst]
__global__ __launch_bounds__(256) void k_edge(
    const u16* __restrict__ x, float* __restrict__ aggr,
    const int* __restrict__ src, const int* __restrict__ dst,
    const int* __restrict__ et, const float* __restrict__ ef,
    const float* __restrict__ w1, const float* __restrict__ b1,
    const float* __restrict__ w2, const float* __restrict__ b2,
    const float* __restrict__ wc, const float* __restrict__ wv)
{
  __shared__ float sW1[4096];
  __shared__ float sWcv[8192];   // [0:4096) = padded w_cons, [4096:8192) = w_vars
  __shared__ float sw2[64];
  __shared__ float sb1[64];
  for (int i = threadIdx.x; i < 4096; i += 256) {
    sW1[i] = w1[i];
    sWcv[4096 + i] = wv[i];
    int k = i >> 6, d = i & 63;
    sWcv[i] = (k < 62 && d < 62) ? wc[k * 62 + d] : 0.f;
  }
  if (threadIdx.x < 64) {
    sw2[threadIdx.x] = w2[threadIdx.x];
    sb1[threadIdx.x] = b1[threadIdx.x];
  }
  __syncthreads();

  int e = blockIdx.x * 256 + threadIdx.x;
  if (e >= NEDGE) return;
  int s = src[e], dn = dst[e], t = et[e] & 1;
  float effv = ef[s];
  float fb2 = b2[0];

  float xj[64];
  const uint4* xrow = reinterpret_cast<const uint4*>(x + (size_t)s * 64);
#pragma unroll
  for (int j = 0; j < 8; ++j) {
    uint4 p = xrow[j];
    xj[j * 8 + 0] = cvlo(p.x); xj[j * 8 + 1] = cvhi(p.x);
    xj[j * 8 + 2] = cvlo(p.y); xj[j * 8 + 3] = cvhi(p.y);
    xj[j * 8 + 4] = cvlo(p.z); xj[j * 8 + 5] = cvhi(p.z);
    xj[j * 8 + 6] = cvlo(p.w); xj[j * 8 + 7] = cvhi(p.w);
  }

  // var_assign = (sigmoid(xj@W1+b1) . w2 + b2) * ef[src]
  float va = fb2;
#pragma unroll 1
  for (int dd = 0; dd < 64; dd += 4) {
    float a0 = sb1[dd], a1 = sb1[dd + 1], a2 = sb1[dd + 2], a3 = sb1[dd + 3];
#pragma unroll
    for (int k = 0; k < 64; ++k) {
      const float4 w = *reinterpret_cast<const float4*>(&sW1[k * 64 + dd]);
      float xv = xj[k];
      a0 = fmaf(xv, w.x, a0); a1 = fmaf(xv, w.y, a1);
      a2 = fmaf(xv, w.z, a2); a3 = fmaf(xv, w.w, a3);
    }
    va = fmaf(sw2[dd],     sigmoidf_(a0), va);
    va = fmaf(sw2[dd + 1], sigmoidf_(a1), va);
    va = fmaf(sw2[dd + 2], sigmoidf_(a2), va);
    va = fmaf(sw2[dd + 3], sigmoidf_(a3), va);
  }
  va *= effv;

  // unified message matmul (per-lane LDS base select; wc zero-padded)
  const float* Wb = sWcv + (t << 12);
  float* arow = aggr + (size_t)dn * 64;
#pragma unroll 1
  for (int dd = 0; dd < 64; dd += 4) {
    float a0 = 0.f, a1 = 0.f, a2 = 0.f, a3 = 0.f;
#pragma unroll
    for (int k = 0; k < 64; ++k) {
      const float4 w = *reinterpret_cast<const float4*>(&Wb[k * 64 + dd]);
      float xv = xj[k];
      a0 = fmaf(xv, w.x, a0); a1 = fmaf(xv, w.y, a1);
      a2 = fmaf(xv, w.z, a2); a3 = fmaf(xv, w.w, a3);
    }
    if (dd == 60 && t == 0) { a2 = xj[62]; a3 = va; }
    unsafeAtomicAdd(arow + dd + 0, a0);
    unsafeAtomicAdd(arow + dd + 1, a1);
    unsafeAtomicAdd(arow + dd + 2, a2);
    unsafeAtomicAdd(arow + dd + 3, a3);
  }
}

// ---- x[l+1] = relu(aggr) (bf16), then refill aggr with next bias ---------
__global__ void k_relu_store(float4* __restrict__ aggr, u16* __restrict__ xout,
                             const float* __restrict__ bias_next)
{
  int i = blockIdx.x * 256 + threadIdx.x;   // exactly NNODE*16 threads
  float4 v = aggr[i];
  u32 lo = (u32)f2bf(fmaxf(v.x, 0.f)) | ((u32)f2bf(fmaxf(v.y, 0.f)) << 16);
  u32 hi = (u32)f2bf(fmaxf(v.z, 0.f)) | ((u32)f2bf(fmaxf(v.w, 0.f)) << 16);
  reinterpret_cast<uint2*>(xout)[i] = make_uint2(lo, hi);
  int d = (i & 15) * 4;
  aggr[i] = make_float4(bias_next[d], bias_next[d + 1], bias_next[d + 2], bias_next[d + 3]);
}

// ---- head fc1: [NVAR,320]@[320,64] with fc1 staged in 2 LDS phases -------
__global__ __launch_bounds__(256) void k_head1(
    const u16* __restrict__ xs,      // [5][NNODE][64] bf16
    const int* __restrict__ assoc,
    const float* __restrict__ fw,    // [320][64]
    const float* __restrict__ fb,    // [64]
    float* __restrict__ hout)        // [NVAR][64]
{
  __shared__ float sw[160 * 64];     // 40 KB
  int i = blockIdx.x * 256 + threadIdx.x;
  bool act = (i < NVAR);
  int r = act ? assoc[i] : 0;
  float acc[64];
#pragma unroll
  for (int d = 0; d < 64; ++d) acc[d] = fb[d];
#pragma unroll 1
  for (int ph = 0; ph < 2; ++ph) {
    __syncthreads();
    for (int j = threadIdx.x; j < 160 * 64; j += 256) sw[j] = fw[ph * 160 * 64 + j];
    __syncthreads();
#pragma unroll 1
    for (int c = 0; c < 20; ++c) {
      int kb = ph * 160 + c * 8;
      int p = kb >> 6, off = kb & 63;
      uint4 u = *reinterpret_cast<const uint4*>(xs + ((size_t)p * NNODE + r) * 64 + off);
      float xv[8] = {cvlo(u.x), cvhi(u.x), cvlo(u.y), cvhi(u.y),
                     cvlo(u.z), cvhi(u.z), cvlo(u.w), cvhi(u.w)};
#pragma unroll
      for (int jj = 0; jj < 8; ++jj) {
        const float* wr = &sw[(c * 8 + jj) * 64];
#pragma unroll
        for (int d = 0; d < 64; d += 4) {
          const float4 w = *reinterpret_cast<const float4*>(&wr[d]);
          acc[d]     = fmaf(xv[jj], w.x, acc[d]);
          acc[d + 1] = fmaf(xv[jj], w.y, acc[d + 1]);
          acc[d + 2] = fmaf(xv[jj], w.z, acc[d + 2]);
          acc[d + 3] = fmaf(xv[jj], w.w, acc[d + 3]);
        }
      }
    }
  }
  if (!act) return;
  float* orow = hout + (size_t)i * 64;
#pragma unroll
  for (int d = 0; d < 64; d += 4) {
    *reinterpret_cast<float4*>(orow + d) = make_float4(
        fmaxf(acc[d], 0.f), fmaxf(acc[d + 1], 0.f),
        fmaxf(acc[d + 2], 0.f), fmaxf(acc[d + 3], 0.f));
  }
}

// ---- head fc2/fc3: relu([NVAR,64]@[64,64]+b) -----------------------------
__global__ __launch_bounds__(256) void k_dense64(
    const float* __restrict__ hin, const float* __restrict__ w,
    const float* __restrict__ b, float* __restrict__ hout)
{
  __shared__ float sw[4096];
  __shared__ float sb[64];
  for (int j = threadIdx.x; j < 4096; j += 256) sw[j] = w[j];
  if (threadIdx.x < 64) sb[threadIdx.x] = b[threadIdx.x];
  __syncthreads();
  int i = blockIdx.x * 256 + threadIdx.x;
  if (i >= NVAR) return;
  float xr[64];
  const float4* irow = reinterpret_cast<const float4*>(hin + (size_t)i * 64);
#pragma unroll
  for (int j = 0; j < 16; ++j) {
    float4 v = irow[j];
    xr[j * 4] = v.x; xr[j * 4 + 1] = v.y; xr[j * 4 + 2] = v.z; xr[j * 4 + 3] = v.w;
  }
  float* orow = hout + (size_t)i * 64;
#pragma unroll 1
  for (int dd = 0; dd < 64; dd += 4) {
    float a0 = sb[dd], a1 = sb[dd + 1], a2 = sb[dd + 2], a3 = sb[dd + 3];
#pragma unroll
    for (int k = 0; k < 64; ++k) {
      const float4 w4 = *reinterpret_cast<const float4*>(&sw[k * 64 + dd]);
      float xv = xr[k];
      a0 = fmaf(xv, w4.x, a0); a1 = fmaf(xv, w4.y, a1);
      a2 = fmaf(xv, w4.z, a2); a3 = fmaf(xv, w4.w, a3);
    }
    *reinterpret_cast<float4*>(orow + dd) = make_float4(
        fmaxf(a0, 0.f), fmaxf(a1, 0.f), fmaxf(a2, 0.f), fmaxf(a3, 0.f));
  }
}

// ---- head fc4: dot + bias -> out ----------------------------------------
__global__ __launch_bounds__(256) void k_head4(
    const float* __restrict__ hin, const float* __restrict__ w,
    const float* __restrict__ b, float* __restrict__ out)
{
  __shared__ float sw[64];
  if (threadIdx.x < 64) sw[threadIdx.x] = w[threadIdx.x];
  __syncthreads();
  int i = blockIdx.x * 256 + threadIdx.x;
  if (i >= NVAR) return;
  float acc = b[0];
  const float4* irow = reinterpret_cast<const float4*>(hin + (size_t)i * 64);
#pragma unroll
  for (int j = 0; j < 16; ++j) {
    float4 v = irow[j];
    acc = fmaf(v.x, sw[j * 4], acc);
    acc = fmaf(v.y, sw[j * 4 + 1], acc);
    acc = fmaf(v.z, sw[j * 4 + 2], acc);
    acc = fmaf(v.w, sw[j * 4 + 3], acc);
  }
  out[i] = acc;
}

// ---- launch --------------------------------------------------------------
extern "C" void kernel_launch(void* const* d_in, const int* in_sizes, int n_in,
                              void* d_out, int out_size, void* d_ws, size_t ws_size,
                              hipStream_t stream)
{
  (void)in_sizes; (void)n_in; (void)out_size; (void)ws_size;
  const float* var_nf = (const float*)d_in[0];
  const float* con_nf = (const float*)d_in[1];
  const float* edge_f = (const float*)d_in[2];
  const int*   eidx   = (const int*)d_in[3];
  const int*   etyp   = (const int*)d_in[4];
  const int*   avar   = (const int*)d_in[5];
  const int*   acon   = (const int*)d_in[6];
  const float* vw1 = (const float*)d_in[7];
  const float* vb1 = (const float*)d_in[8];
  const float* vw2 = (const float*)d_in[9];
  const float* vb2 = (const float*)d_in[10];
  const float* cw1 = (const float*)d_in[11];
  const float* cb1 = (const float*)d_in[12];
  const float* cw2 = (const float*)d_in[13];
  const float* cb2 = (const float*)d_in[14];
  const float* hw1 = (const float*)d_in[15];
  const float* hb1 = (const float*)d_in[16];
  const float* hw2 = (const float*)d_in[17];
  const float* hb2 = (const float*)d_in[18];
  const float* wco = (const float*)d_in[19];
  const float* wva = (const float*)d_in[20];
  const float* bia = (const float*)d_in[21];
  const float* f1w = (const float*)d_in[22];
  const float* f1b = (const float*)d_in[23];
  const float* f2w = (const float*)d_in[24];
  const float* f2b = (const float*)d_in[25];
  const float* f3w = (const float*)d_in[26];
  const float* f3b = (const float*)d_in[27];
  const float* f4w = (const float*)d_in[28];
  const float* f4b = (const float*)d_in[29];

  char* ws = (char*)d_ws;
  u16*   xs   = (u16*)ws;                       // 5 * NNODE*64*2 = 64,000,000 B
  float* aggr = (float*)(ws + 64000000);        // NNODE*64*4 = 25,600,000 B
  float* hA   = (float*)(ws + 64000000);        // reuse aggr after layers
  float* hB   = (float*)(ws + 79360000);        // 15,360,000 B

  const int* esrc = eidx;
  const int* edst = eidx + NEDGE;

  hipMemsetAsync(xs, 0, (size_t)NNODE * 64 * 2, stream);
  k_var_init<<<(NVAR + 255) / 256, 256, 0, stream>>>(var_nf, avar, vw1, vb1, vw2, vb2, xs);
  k_con_init<<<(NCON + 255) / 256, 256, 0, stream>>>(con_nf, acon, cw1, cb1, cw2, cb2, xs);
  k_aggr_init<<<NNODE * 16 / 256, 256, 0, stream>>>((float4*)aggr, bia);

  for (int l = 0; l < 4; ++l) {
    u16* xin  = xs + (size_t)l * NNODE * 64;
    u16* xout = xs + (size_t)(l + 1) * NNODE * 64;
    k_edge<<<(NEDGE + 255) / 256, 256, 0, stream>>>(
        xin, aggr, esrc, edst, etyp, edge_f,
        hw1 + l * 4096, hb1 + l * 64, hw2 + l * 64, hb2 + l,
        wco + l * 3844, wva + l * 4096);
    int nl = (l + 1) & 3;
    k_relu_store<<<NNODE * 16 / 256, 256, 0, stream>>>((float4*)aggr, xout, bia + nl * 64);
  }

  k_head1<<<(NVAR + 255) / 256, 256, 0, stream>>>(xs, avar, f1w, f1b, hA);
  k_dense64<<<(NVAR + 255) / 256, 256, 0, stream>>>(hA, f2w, f2b, hB);
  k_dense64<<<(NVAR + 255) / 256, 256, 0, stream>>>(hB, f3w, f3b, hA);
  k_head4<<<(NVAR + 255) / 256, 256, 0, stream>>>(hA, f4w, f4b, (float*)d_out);
}

// Round 2
// 923.892 us; speedup vs baseline: 7.7590x; 7.7590x over previous
//
#include <hip/hip_runtime.h>
#include <hip/hip_bf16.h>

typedef unsigned int u32;
typedef unsigned short u16;

#define NNODE 100000
#define NVAR  60000
#define NCON  40000
#define NEDGE 500000
#define SLOTCAP 32

// ---- helpers -------------------------------------------------------------
__device__ __forceinline__ u16 f2bf(float f) {
  u32 u = __float_as_uint(f);
  u32 r = (u + 0x7fffu + ((u >> 16) & 1u)) >> 16;   // RNE
  return (u16)r;
}
__device__ __forceinline__ float cvlo(u32 p) { return __uint_as_float(p << 16); }
__device__ __forceinline__ float cvhi(u32 p) { return __uint_as_float(p & 0xffff0000u); }
__device__ __forceinline__ float sigmoidf_(float x) {
  return __builtin_amdgcn_rcpf(1.0f + __expf(-x));
}

// ---- node init: var nodes -> x0 rows [mlp(62), v, 1] ---------------------
__global__ __launch_bounds__(256) void k_var_init(
    const float* __restrict__ vf, const int* __restrict__ assoc,
    const float* __restrict__ w1, const float* __restrict__ b1,
    const float* __restrict__ w2, const float* __restrict__ b2,
    u16* __restrict__ x0)
{
  __shared__ float sw2[62 * 62];
  __shared__ float sw1[62], sb1[62], sb2[62];
  for (int i = threadIdx.x; i < 62 * 62; i += 256) sw2[i] = w2[i];
  if (threadIdx.x < 62) {
    sw1[threadIdx.x] = w1[threadIdx.x];
    sb1[threadIdx.x] = b1[threadIdx.x];
    sb2[threadIdx.x] = b2[threadIdx.x];
  }
  __syncthreads();
  int i = blockIdx.x * 256 + threadIdx.x;
  if (i >= NVAR) return;
  float v = vf[i];
  float h[62];
#pragma unroll
  for (int j = 0; j < 62; ++j) h[j] = fmaxf(fmaf(v, sw1[j], sb1[j]), 0.f);
  int r = assoc[i];
  u16* orow = x0 + (size_t)r * 64;
#pragma unroll 1
  for (int d = 0; d < 62; ++d) {
    float acc = sb2[d];
#pragma unroll
    for (int k = 0; k < 62; ++k) acc = fmaf(h[k], sw2[k * 62 + d], acc);
    orow[d] = f2bf(acc);
  }
  orow[62] = f2bf(v);
  orow[63] = 0x3f80;  // 1.0 bf16
}

// ---- node init: con nodes -> x0 rows [mlp(63), c] ------------------------
__global__ __launch_bounds__(256) void k_con_init(
    const float* __restrict__ cf, const int* __restrict__ assoc,
    const float* __restrict__ w1, const float* __restrict__ b1,
    const float* __restrict__ w2, const float* __restrict__ b2,
    u16* __restrict__ x0)
{
  __shared__ float sw2[63 * 63];
  __shared__ float sw1[63], sb1[63], sb2[63];
  for (int i = threadIdx.x; i < 63 * 63; i += 256) sw2[i] = w2[i];
  if (threadIdx.x < 63) {
    sw1[threadIdx.x] = w1[threadIdx.x];
    sb1[threadIdx.x] = b1[threadIdx.x];
    sb2[threadIdx.x] = b2[threadIdx.x];
  }
  __syncthreads();
  int i = blockIdx.x * 256 + threadIdx.x;
  if (i >= NCON) return;
  float c = cf[i];
  float h[63];
#pragma unroll
  for (int j = 0; j < 63; ++j) h[j] = fmaxf(fmaf(c, sw1[j], sb1[j]), 0.f);
  int r = assoc[i];
  u16* orow = x0 + (size_t)r * 64;
#pragma unroll 1
  for (int d = 0; d < 63; ++d) {
    float acc = sb2[d];
#pragma unroll
    for (int k = 0; k < 63; ++k) acc = fmaf(h[k], sw2[k * 63 + d], acc);
    orow[d] = f2bf(acc);
  }
  orow[63] = f2bf(c);
}

// ---- CSR-ish bucket build: slots[d][pos] = src | (type<<20) --------------
__global__ __launch_bounds__(256) void k_scatter(
    const int* __restrict__ src, const int* __restrict__ dst,
    const int* __restrict__ et, int* __restrict__ cnt, int* __restrict__ slots)
{
  int e = blockIdx.x * 256 + threadIdx.x;
  if (e >= NEDGE) return;
  int d = dst[e];
  int pos = atomicAdd(&cnt[d], 1);
  if (pos < SLOTCAP) slots[d * SLOTCAP + pos] = src[e] | ((et[e] & 1) << 20);
}

// ---- per-layer NODE table kernel ----------------------------------------
// tbl0[n] = [x[n][:62]@Wc, x[n][62], (sigmoid(x@W1+b1).w2+b2)*ef[n]]
// tbl1[n] = x[n]@Wv
__global__ __launch_bounds__(256) void k_node(
    const u16* __restrict__ x, const float* __restrict__ ef,
    const float* __restrict__ w1, const float* __restrict__ b1,
    const float* __restrict__ w2, const float* __restrict__ b2,
    const float* __restrict__ wc, const float* __restrict__ wv,
    float* __restrict__ tbl)
{
  __shared__ float sW1[4096];
  __shared__ float sWcv[8192];   // [0:4096) = padded w_cons, [4096:8192) = w_vars
  __shared__ float sw2[64];
  __shared__ float sb1[64];
  for (int i = threadIdx.x; i < 4096; i += 256) {
    sW1[i] = w1[i];
    sWcv[4096 + i] = wv[i];
    int k = i >> 6, d = i & 63;
    sWcv[i] = (k < 62 && d < 62) ? wc[k * 62 + d] : 0.f;
  }
  if (threadIdx.x < 64) {
    sw2[threadIdx.x] = w2[threadIdx.x];
    sb1[threadIdx.x] = b1[threadIdx.x];
  }
  __syncthreads();

  int n = blockIdx.x * 256 + threadIdx.x;
  if (n >= NNODE) return;

  float xj[64];
  const uint4* xrow = reinterpret_cast<const uint4*>(x + (size_t)n * 64);
#pragma unroll
  for (int j = 0; j < 8; ++j) {
    uint4 p = xrow[j];
    xj[j * 8 + 0] = cvlo(p.x); xj[j * 8 + 1] = cvhi(p.x);
    xj[j * 8 + 2] = cvlo(p.y); xj[j * 8 + 3] = cvhi(p.y);
    xj[j * 8 + 4] = cvlo(p.z); xj[j * 8 + 5] = cvhi(p.z);
    xj[j * 8 + 6] = cvlo(p.w); xj[j * 8 + 7] = cvhi(p.w);
  }

  // gate: va = (sigmoid(x@W1+b1) . w2 + b2) * ef[n]
  float va = b2[0];
#pragma unroll 1
  for (int dd = 0; dd < 64; dd += 4) {
    float a0 = sb1[dd], a1 = sb1[dd + 1], a2 = sb1[dd + 2], a3 = sb1[dd + 3];
#pragma unroll
    for (int k = 0; k < 64; ++k) {
      const float4 w = *reinterpret_cast<const float4*>(&sW1[k * 64 + dd]);
      float xv = xj[k];
      a0 = fmaf(xv, w.x, a0); a1 = fmaf(xv, w.y, a1);
      a2 = fmaf(xv, w.z, a2); a3 = fmaf(xv, w.w, a3);
    }
    va = fmaf(sw2[dd],     sigmoidf_(a0), va);
    va = fmaf(sw2[dd + 1], sigmoidf_(a1), va);
    va = fmaf(sw2[dd + 2], sigmoidf_(a2), va);
    va = fmaf(sw2[dd + 3], sigmoidf_(a3), va);
  }
  va *= ef[n];

  // tbl1 = x @ Wv
  float* t1row = tbl + 6400000 + (size_t)n * 64;
#pragma unroll 1
  for (int dd = 0; dd < 64; dd += 4) {
    float a0 = 0.f, a1 = 0.f, a2 = 0.f, a3 = 0.f;
#pragma unroll
    for (int k = 0; k < 64; ++k) {
      const float4 w = *reinterpret_cast<const float4*>(&sWcv[4096 + k * 64 + dd]);
      float xv = xj[k];
      a0 = fmaf(xv, w.x, a0); a1 = fmaf(xv, w.y, a1);
      a2 = fmaf(xv, w.z, a2); a3 = fmaf(xv, w.w, a3);
    }
    *reinterpret_cast<float4*>(t1row + dd) = make_float4(a0, a1, a2, a3);
  }

  // tbl0 = [x[:62]@Wc (padded), x[62], va]
  float* t0row = tbl + (size_t)n * 64;
#pragma unroll 1
  for (int dd = 0; dd < 64; dd += 4) {
    float a0 = 0.f, a1 = 0.f, a2 = 0.f, a3 = 0.f;
#pragma unroll
    for (int k = 0; k < 64; ++k) {
      const float4 w = *reinterpret_cast<const float4*>(&sWcv[k * 64 + dd]);
      float xv = xj[k];
      a0 = fmaf(xv, w.x, a0); a1 = fmaf(xv, w.y, a1);
      a2 = fmaf(xv, w.z, a2); a3 = fmaf(xv, w.w, a3);
    }
    if (dd == 60) { a2 = xj[62]; a3 = va; }
    *reinterpret_cast<float4*>(t0row + dd) = make_float4(a0, a1, a2, a3);
  }
}

// ---- aggregation: one wave per dst node, no atomics ----------------------
// x_next[n] = relu(bias + sum_{slots} tbl[t][s])  stored bf16
__global__ __launch_bounds__(256) void k_aggr(
    const float* __restrict__ tbl, const int* __restrict__ cnt,
    const int* __restrict__ slots, const float* __restrict__ bias,
    u16* __restrict__ xout)
{
  int wid = threadIdx.x >> 6, lane = threadIdx.x & 63;
  int n = blockIdx.x * 4 + wid;            // grid = 25000 blocks exactly
  float acc = bias[lane];
  int deg = cnt[n]; if (deg > SLOTCAP) deg = SLOTCAP;
  const int* sl = slots + (size_t)n * SLOTCAP;
  int v = (deg > 0) ? sl[0] : 0;
#pragma unroll 1
  for (int j = 0; j < deg; ++j) {
    int vn = (j + 1 < deg) ? sl[j + 1] : 0;  // prefetch next slot
    int s = v & 0xFFFFF, t = v >> 20;
    acc += tbl[((size_t)t * NNODE + s) * 64 + lane];
    v = vn;
  }
  xout[(size_t)n * 64 + lane] = f2bf(fmaxf(acc, 0.f));
}

// ---- head fc1: [NVAR,320]@[320,64] with fc1 staged in 2 LDS phases -------
__global__ __launch_bounds__(256) void k_head1(
    const u16* __restrict__ xs,      // [5][NNODE][64] bf16
    const int* __restrict__ assoc,
    const float* __restrict__ fw,    // [320][64]
    const float* __restrict__ fb,    // [64]
    float* __restrict__ hout)        // [NVAR][64]
{
  __shared__ float sw[160 * 64];     // 40 KB
  int i = blockIdx.x * 256 + threadIdx.x;
  bool act = (i < NVAR);
  int r = act ? assoc[i] : 0;
  float acc[64];
#pragma unroll
  for (int d = 0; d < 64; ++d) acc[d] = fb[d];
#pragma unroll 1
  for (int ph = 0; ph < 2; ++ph) {
    __syncthreads();
    for (int j = threadIdx.x; j < 160 * 64; j += 256) sw[j] = fw[ph * 160 * 64 + j];
    __syncthreads();
#pragma unroll 1
    for (int c = 0; c < 20; ++c) {
      int kb = ph * 160 + c * 8;
      int p = kb >> 6, off = kb & 63;
      uint4 u = *reinterpret_cast<const uint4*>(xs + ((size_t)p * NNODE + r) * 64 + off);
      float xv[8] = {cvlo(u.x), cvhi(u.x), cvlo(u.y), cvhi(u.y),
                     cvlo(u.z), cvhi(u.z), cvlo(u.w), cvhi(u.w)};
#pragma unroll
      for (int jj = 0; jj < 8; ++jj) {
        const float* wr = &sw[(c * 8 + jj) * 64];
#pragma unroll
        for (int d = 0; d < 64; d += 4) {
          const float4 w = *reinterpret_cast<const float4*>(&wr[d]);
          acc[d]     = fmaf(xv[jj], w.x, acc[d]);
          acc[d + 1] = fmaf(xv[jj], w.y, acc[d + 1]);
          acc[d + 2] = fmaf(xv[jj], w.z, acc[d + 2]);
          acc[d + 3] = fmaf(xv[jj], w.w, acc[d + 3]);
        }
      }
    }
  }
  if (!act) return;
  float* orow = hout + (size_t)i * 64;
#pragma unroll
  for (int d = 0; d < 64; d += 4) {
    *reinterpret_cast<float4*>(orow + d) = make_float4(
        fmaxf(acc[d], 0.f), fmaxf(acc[d + 1], 0.f),
        fmaxf(acc[d + 2], 0.f), fmaxf(acc[d + 3], 0.f));
  }
}

// ---- head fc2/fc3: relu([NVAR,64]@[64,64]+b) -----------------------------
__global__ __launch_bounds__(256) void k_dense64(
    const float* __restrict__ hin, const float* __restrict__ w,
    const float* __restrict__ b, float* __restrict__ hout)
{
  __shared__ float sw[4096];
  __shared__ float sb[64];
  for (int j = threadIdx.x; j < 4096; j += 256) sw[j] = w[j];
  if (threadIdx.x < 64) sb[threadIdx.x] = b[threadIdx.x];
  __syncthreads();
  int i = blockIdx.x * 256 + threadIdx.x;
  if (i >= NVAR) return;
  float xr[64];
  const float4* irow = reinterpret_cast<const float4*>(hin + (size_t)i * 64);
#pragma unroll
  for (int j = 0; j < 16; ++j) {
    float4 v = irow[j];
    xr[j * 4] = v.x; xr[j * 4 + 1] = v.y; xr[j * 4 + 2] = v.z; xr[j * 4 + 3] = v.w;
  }
  float* orow = hout + (size_t)i * 64;
#pragma unroll 1
  for (int dd = 0; dd < 64; dd += 4) {
    float a0 = sb[dd], a1 = sb[dd + 1], a2 = sb[dd + 2], a3 = sb[dd + 3];
#pragma unroll
    for (int k = 0; k < 64; ++k) {
      const float4 w4 = *reinterpret_cast<const float4*>(&sw[k * 64 + dd]);
      float xv = xr[k];
      a0 = fmaf(xv, w4.x, a0); a1 = fmaf(xv, w4.y, a1);
      a2 = fmaf(xv, w4.z, a2); a3 = fmaf(xv, w4.w, a3);
    }
    *reinterpret_cast<float4*>(orow + dd) = make_float4(
        fmaxf(a0, 0.f), fmaxf(a1, 0.f), fmaxf(a2, 0.f), fmaxf(a3, 0.f));
  }
}

// ---- head fc4: dot + bias -> out ----------------------------------------
__global__ __launch_bounds__(256) void k_head4(
    const float* __restrict__ hin, const float* __restrict__ w,
    const float* __restrict__ b, float* __restrict__ out)
{
  __shared__ float sw[64];
  if (threadIdx.x < 64) sw[threadIdx.x] = w[threadIdx.x];
  __syncthreads();
  int i = blockIdx.x * 256 + threadIdx.x;
  if (i >= NVAR) return;
  float acc = b[0];
  const float4* irow = reinterpret_cast<const float4*>(hin + (size_t)i * 64);
#pragma unroll
  for (int j = 0; j < 16; ++j) {
    float4 v = irow[j];
    acc = fmaf(v.x, sw[j * 4], acc);
    acc = fmaf(v.y, sw[j * 4 + 1], acc);
    acc = fmaf(v.z, sw[j * 4 + 2], acc);
    acc = fmaf(v.w, sw[j * 4 + 3], acc);
  }
  out[i] = acc;
}

// ---- launch --------------------------------------------------------------
extern "C" void kernel_launch(void* const* d_in, const int* in_sizes, int n_in,
                              void* d_out, int out_size, void* d_ws, size_t ws_size,
                              hipStream_t stream)
{
  (void)in_sizes; (void)n_in; (void)out_size; (void)ws_size;
  const float* var_nf = (const float*)d_in[0];
  const float* con_nf = (const float*)d_in[1];
  const float* edge_f = (const float*)d_in[2];
  const int*   eidx   = (const int*)d_in[3];
  const int*   etyp   = (const int*)d_in[4];
  const int*   avar   = (const int*)d_in[5];
  const int*   acon   = (const int*)d_in[6];
  const float* vw1 = (const float*)d_in[7];
  const float* vb1 = (const float*)d_in[8];
  const float* vw2 = (const float*)d_in[9];
  const float* vb2 = (const float*)d_in[10];
  const float* cw1 = (const float*)d_in[11];
  const float* cb1 = (const float*)d_in[12];
  const float* cw2 = (const float*)d_in[13];
  const float* cb2 = (const float*)d_in[14];
  const float* hw1 = (const float*)d_in[15];
  const float* hb1 = (const float*)d_in[16];
  const float* hw2 = (const float*)d_in[17];
  const float* hb2 = (const float*)d_in[18];
  const float* wco = (const float*)d_in[19];
  const float* wva = (const float*)d_in[20];
  const float* bia = (const float*)d_in[21];
  const float* f1w = (const float*)d_in[22];
  const float* f1b = (const float*)d_in[23];
  const float* f2w = (const float*)d_in[24];
  const float* f2b = (const float*)d_in[25];
  const float* f3w = (const float*)d_in[26];
  const float* f3b = (const float*)d_in[27];
  const float* f4w = (const float*)d_in[28];
  const float* f4b = (const float*)d_in[29];

  char* ws = (char*)d_ws;
  // layout: xs [0,64M) | tbl f32 [64M,115.2M) | cnt [115.2M,115.6M) | slots [115.6M,128.4M)
  // head hA/hB overlay the tbl region (dead after the 4 layers).
  u16*   xs    = (u16*)ws;
  float* tbl   = (float*)(ws + 64000000);
  int*   cnt   = (int*)(ws + 115200000);
  int*   slots = (int*)(ws + 115600000);
  float* hA    = (float*)(ws + 64000000);
  float* hB    = (float*)(ws + 79360000);

  const int* esrc = eidx;
  const int* edst = eidx + NEDGE;

  k_var_init<<<(NVAR + 255) / 256, 256, 0, stream>>>(var_nf, avar, vw1, vb1, vw2, vb2, xs);
  k_con_init<<<(NCON + 255) / 256, 256, 0, stream>>>(con_nf, acon, cw1, cb1, cw2, cb2, xs);
  hipMemsetAsync(cnt, 0, NNODE * sizeof(int), stream);
  k_scatter<<<(NEDGE + 255) / 256, 256, 0, stream>>>(esrc, edst, etyp, cnt, slots);

  for (int l = 0; l < 4; ++l) {
    u16* xin  = xs + (size_t)l * NNODE * 64;
    u16* xout = xs + (size_t)(l + 1) * NNODE * 64;
    k_node<<<(NNODE + 255) / 256, 256, 0, stream>>>(
        xin, edge_f,
        hw1 + l * 4096, hb1 + l * 64, hw2 + l * 64, hb2 + l,
        wco + l * 3844, wva + l * 4096, tbl);
    k_aggr<<<NNODE / 4, 256, 0, stream>>>(tbl, cnt, slots, bia + l * 64, xout);
  }

  k_head1<<<(NVAR + 255) / 256, 256, 0, stream>>>(xs, avar, f1w, f1b, hA);
  k_dense64<<<(NVAR + 255) / 256, 256, 0, stream>>>(hA, f2w, f2b, hB);
  k_dense64<<<(NVAR + 255) / 256, 256, 0, stream>>>(hB, f3w, f3b, hA);
  k_head4<<<(NVAR + 255) / 256, 256, 0, stream>>>(hA, f4w, f4b, (float*)d_out);
}

// Round 3
// 715.998 us; speedup vs baseline: 10.0118x; 1.2904x over previous
//
#include <hip/hip_runtime.h>
#include <hip/hip_bf16.h>

typedef unsigned int u32;
typedef unsigned short u16;
typedef __attribute__((ext_vector_type(8))) short frag8;   // 8 bf16 (4 VGPRs)
typedef __attribute__((ext_vector_type(4))) float f32x4;   // MFMA C/D

#define NNODE 100000
#define NVAR  60000
#define NCON  40000
#define NEDGE 500000
#define SLOTCAP 32
#define TBL1 6400000UL

// ---- helpers -------------------------------------------------------------
__device__ __forceinline__ u16 f2bf(float f) {
  u32 u = __float_as_uint(f);
  u32 r = (u + 0x7fffu + ((u >> 16) & 1u)) >> 16;   // RNE
  return (u16)r;
}
__device__ __forceinline__ float bf2f(u16 u) { return __uint_as_float(((u32)u) << 16); }
__device__ __forceinline__ float cvlo(u32 p) { return __uint_as_float(p << 16); }
__device__ __forceinline__ float cvhi(u32 p) { return __uint_as_float(p & 0xffff0000u); }
__device__ __forceinline__ float sigmoidf_(float x) {
  return __builtin_amdgcn_rcpf(1.0f + __expf(-x));
}
// split w into hi+lo bf16 and write into pre-swizzled B-fragment LDS:
// frag layout: sB[frag*512 + lane*8 + j], where for sub-block (ks,nt):
//   lane = (n&15) | (((k&31)>>3)<<4), j = k&7   (B[k][n] of a 32x16 tile)
__device__ __forceinline__ void stage_frag(u16* sB, int fr_hi, int fr_lo,
                                           int k, int n, float w) {
  u16 hi = f2bf(w);
  u16 lo = f2bf(w - bf2f(hi));
  int kl = k & 31;
  int lane = (n & 15) | ((kl >> 3) << 4);
  int j = kl & 7;
  sB[fr_hi * 512 + lane * 8 + j] = hi;
  sB[fr_lo * 512 + lane * 8 + j] = lo;
}

// ---- node init: var nodes -> x0 rows [mlp(62), v, 1] ---------------------
__global__ __launch_bounds__(256) void k_var_init(
    const float* __restrict__ vf, const int* __restrict__ assoc,
    const float* __restrict__ w1, const float* __restrict__ b1,
    const float* __restrict__ w2, const float* __restrict__ b2,
    u16* __restrict__ x0)
{
  __shared__ float sw2[62 * 64];            // padded cols to 64, pad=0
  __shared__ float sw1[62], sb1[62], sb2[64];
  for (int i = threadIdx.x; i < 62 * 64; i += 256) {
    int k = i >> 6, d = i & 63;
    sw2[i] = (d < 62) ? w2[k * 62 + d] : 0.f;
  }
  if (threadIdx.x < 62) {
    sw1[threadIdx.x] = w1[threadIdx.x];
    sb1[threadIdx.x] = b1[threadIdx.x];
  }
  if (threadIdx.x < 64) sb2[threadIdx.x] = (threadIdx.x < 62) ? b2[threadIdx.x] : 0.f;
  __syncthreads();
  int i = blockIdx.x * 256 + threadIdx.x;
  if (i >= NVAR) return;
  float v = vf[i];
  float h[62];
#pragma unroll
  for (int j = 0; j < 62; ++j) h[j] = fmaxf(fmaf(v, sw1[j], sb1[j]), 0.f);
  float o[64];
#pragma unroll 1
  for (int dd = 0; dd < 64; dd += 4) {
    float a0 = sb2[dd], a1 = sb2[dd + 1], a2 = sb2[dd + 2], a3 = sb2[dd + 3];
#pragma unroll
    for (int k = 0; k < 62; ++k) {
      const float4 w = *reinterpret_cast<const float4*>(&sw2[k * 64 + dd]);
      float hv = h[k];
      a0 = fmaf(hv, w.x, a0); a1 = fmaf(hv, w.y, a1);
      a2 = fmaf(hv, w.z, a2); a3 = fmaf(hv, w.w, a3);
    }
    o[dd] = a0; o[dd + 1] = a1; o[dd + 2] = a2; o[dd + 3] = a3;
  }
  o[62] = v; o[63] = 1.0f;
  int r = assoc[i];
  u32* orow = reinterpret_cast<u32*>(x0 + (size_t)r * 64);
#pragma unroll
  for (int j = 0; j < 32; ++j)
    orow[j] = (u32)f2bf(o[2 * j]) | ((u32)f2bf(o[2 * j + 1]) << 16);
}

// ---- node init: con nodes -> x0 rows [mlp(63), c] ------------------------
__global__ __launch_bounds__(256) void k_con_init(
    const float* __restrict__ cf, const int* __restrict__ assoc,
    const float* __restrict__ w1, const float* __restrict__ b1,
    const float* __restrict__ w2, const float* __restrict__ b2,
    u16* __restrict__ x0)
{
  __shared__ float sw2[63 * 64];
  __shared__ float sw1[63], sb1[63], sb2[64];
  for (int i = threadIdx.x; i < 63 * 64; i += 256) {
    int k = i >> 6, d = i & 63;
    sw2[i] = (d < 63) ? w2[k * 63 + d] : 0.f;
  }
  if (threadIdx.x < 63) {
    sw1[threadIdx.x] = w1[threadIdx.x];
    sb1[threadIdx.x] = b1[threadIdx.x];
  }
  if (threadIdx.x < 64) sb2[threadIdx.x] = (threadIdx.x < 63) ? b2[threadIdx.x] : 0.f;
  __syncthreads();
  int i = blockIdx.x * 256 + threadIdx.x;
  if (i >= NCON) return;
  float c = cf[i];
  float h[63];
#pragma unroll
  for (int j = 0; j < 63; ++j) h[j] = fmaxf(fmaf(c, sw1[j], sb1[j]), 0.f);
  float o[64];
#pragma unroll 1
  for (int dd = 0; dd < 64; dd += 4) {
    float a0 = sb2[dd], a1 = sb2[dd + 1], a2 = sb2[dd + 2], a3 = sb2[dd + 3];
#pragma unroll
    for (int k = 0; k < 63; ++k) {
      const float4 w = *reinterpret_cast<const float4*>(&sw2[k * 64 + dd]);
      float hv = h[k];
      a0 = fmaf(hv, w.x, a0); a1 = fmaf(hv, w.y, a1);
      a2 = fmaf(hv, w.z, a2); a3 = fmaf(hv, w.w, a3);
    }
    o[dd] = a0; o[dd + 1] = a1; o[dd + 2] = a2; o[dd + 3] = a3;
  }
  o[63] = c;
  int r = assoc[i];
  u32* orow = reinterpret_cast<u32*>(x0 + (size_t)r * 64);
#pragma unroll
  for (int j = 0; j < 32; ++j)
    orow[j] = (u32)f2bf(o[2 * j]) | ((u32)f2bf(o[2 * j + 1]) << 16);
}

// ---- CSR-ish bucket build: slots[d][pos] = src | (type<<20) --------------
__global__ __launch_bounds__(256) void k_scatter(
    const int* __restrict__ src, const int* __restrict__ dst,
    const int* __restrict__ et, int* __restrict__ cnt, int* __restrict__ slots)
{
  int e = blockIdx.x * 256 + threadIdx.x;
  if (e >= NEDGE) return;
  int d = dst[e];
  int pos = atomicAdd(&cnt[d], 1);
  if (pos < SLOTCAP) slots[d * SLOTCAP + pos] = src[e] | ((et[e] & 1) << 20);
}

// ---- per-layer NODE table kernel (MFMA, split-bf16 weights) --------------
// tbl0[n] = [x[n][:62]@Wc, x[n][62], (sigmoid(x@W1+b1).w2+b2)*ef[n]]
// tbl1[n] = x[n]@Wv        (wave = 32 nodes, 4 waves/block = 128 nodes)
__global__ __launch_bounds__(256) void k_node(
    const u16* __restrict__ x, const float* __restrict__ ef,
    const float* __restrict__ w1, const float* __restrict__ b1,
    const float* __restrict__ w2, const float* __restrict__ b2,
    const float* __restrict__ wc, const float* __restrict__ wv,
    float* __restrict__ tbl)
{
  __shared__ u16 sB[48 * 512];      // 48 KB: 3 mats x 2 splits x 2 ks x 4 nt
  __shared__ float sb1[64], sw2[64];
  for (int idx = threadIdx.x; idx < 3 * 4096; idx += 256) {
    int mat = idx >> 12, e = idx & 4095;
    int k = e >> 6, n = e & 63;
    float w;
    if (mat == 0) w = w1[e];
    else if (mat == 1) w = (k < 62 && n < 62) ? wc[k * 62 + n] : 0.f;
    else w = wv[e];
    int ksp = k >> 5, nt = n >> 4;
    int fr_hi = ((mat * 2 + 0) * 2 + ksp) * 4 + nt;
    int fr_lo = ((mat * 2 + 1) * 2 + ksp) * 4 + nt;
    stage_frag(sB, fr_hi, fr_lo, k, n, w);
  }
  if (threadIdx.x < 64) { sb1[threadIdx.x] = b1[threadIdx.x]; sw2[threadIdx.x] = w2[threadIdx.x]; }
  __syncthreads();

  int wid = threadIdx.x >> 6, lane = threadIdx.x & 63;
  long nb = ((long)blockIdx.x * 4 + wid) * 32;
  if (nb >= NNODE) return;
  int l15 = lane & 15, lg = lane >> 4;

  const f32x4 z = {0.f, 0.f, 0.f, 0.f};
  f32x4 acc[3][2][4];
#pragma unroll
  for (int a = 0; a < 3; ++a)
#pragma unroll
    for (int m = 0; m < 2; ++m)
#pragma unroll
      for (int n = 0; n < 4; ++n) acc[a][m][n] = z;

  const u16* xr0 = x + (nb + l15) * 64 + 8 * lg;
  const u16* xr1 = xr0 + 16 * 64;
#pragma unroll
  for (int ks = 0; ks < 2; ++ks) {
    frag8 a0 = *reinterpret_cast<const frag8*>(xr0 + ks * 32);
    frag8 a1 = *reinterpret_cast<const frag8*>(xr1 + ks * 32);
#pragma unroll
    for (int mat = 0; mat < 3; ++mat) {
#pragma unroll
      for (int n = 0; n < 4; ++n) {
        frag8 bh = *reinterpret_cast<const frag8*>(&sB[((((mat * 2 + 0) * 2 + ks) * 4 + n) * 512) + lane * 8]);
        frag8 bl = *reinterpret_cast<const frag8*>(&sB[((((mat * 2 + 1) * 2 + ks) * 4 + n) * 512) + lane * 8]);
        acc[mat][0][n] = __builtin_amdgcn_mfma_f32_16x16x32_bf16(a0, bh, acc[mat][0][n], 0, 0, 0);
        acc[mat][0][n] = __builtin_amdgcn_mfma_f32_16x16x32_bf16(a0, bl, acc[mat][0][n], 0, 0, 0);
        acc[mat][1][n] = __builtin_amdgcn_mfma_f32_16x16x32_bf16(a1, bh, acc[mat][1][n], 0, 0, 0);
        acc[mat][1][n] = __builtin_amdgcn_mfma_f32_16x16x32_bf16(a1, bl, acc[mat][1][n], 0, 0, 0);
      }
    }
  }

  float b2v = b2[0];
  float b1c[4], w2c[4];
#pragma unroll
  for (int n = 0; n < 4; ++n) { b1c[n] = sb1[n * 16 + l15]; w2c[n] = sw2[n * 16 + l15]; }

#pragma unroll
  for (int m = 0; m < 2; ++m) {
    // gate row-sums: D layout row = 4*lg + r (+16m), col = 16n + l15
    float p0 = 0.f, p1 = 0.f, p2 = 0.f, p3 = 0.f;
#pragma unroll
    for (int n = 0; n < 4; ++n) {
      p0 += sigmoidf_(acc[0][m][n][0] + b1c[n]) * w2c[n];
      p1 += sigmoidf_(acc[0][m][n][1] + b1c[n]) * w2c[n];
      p2 += sigmoidf_(acc[0][m][n][2] + b1c[n]) * w2c[n];
      p3 += sigmoidf_(acc[0][m][n][3] + b1c[n]) * w2c[n];
    }
#pragma unroll
    for (int off = 1; off < 16; off <<= 1) {
      p0 += __shfl_xor(p0, off);
      p1 += __shfl_xor(p1, off);
      p2 += __shfl_xor(p2, off);
      p3 += __shfl_xor(p3, off);
    }
    float pr[4] = {p0, p1, p2, p3};
#pragma unroll
    for (int r = 0; r < 4; ++r) {
      long node = nb + 16 * m + 4 * lg + r;
      float va = (pr[r] + b2v) * ef[node];
      float x62 = bf2f(x[node * 64 + 62]);
#pragma unroll
      for (int n = 0; n < 4; ++n) {
        int col = n * 16 + l15;
        float v0 = acc[1][m][n][r];
        if (col == 62) v0 = x62;
        if (col == 63) v0 = va;
        tbl[node * 64 + col] = v0;
        tbl[TBL1 + node * 64 + col] = acc[2][m][n][r];
      }
    }
  }
}

// ---- aggregation: one wave per dst node, no atomics ----------------------
__global__ __launch_bounds__(256) void k_aggr(
    const float* __restrict__ tbl, const int* __restrict__ cnt,
    const int* __restrict__ slots, const float* __restrict__ bias,
    u16* __restrict__ xout)
{
  int wid = threadIdx.x >> 6, lane = threadIdx.x & 63;
  int n = blockIdx.x * 4 + wid;            // grid = 25000 blocks exactly
  float acc = bias[lane];
  int deg = cnt[n]; if (deg > SLOTCAP) deg = SLOTCAP;
  const int* sl = slots + (size_t)n * SLOTCAP;
  int v = (deg > 0) ? sl[0] : 0;
#pragma unroll 1
  for (int j = 0; j < deg; ++j) {
    int vn = (j + 1 < deg) ? sl[j + 1] : 0;
    int s = v & 0xFFFFF, t = v >> 20;
    acc += tbl[((size_t)t * NNODE + s) * 64 + lane];
    v = vn;
  }
  xout[(size_t)n * 64 + lane] = f2bf(fmaxf(acc, 0.f));
}

// ---- head fc1: [NVAR,320]@[320,64] MFMA, 2 LDS phases, hi/lo out ---------
__global__ __launch_bounds__(256) void k_head1(
    const u16* __restrict__ xs, const int* __restrict__ assoc,
    const float* __restrict__ fw, const float* __restrict__ fb,
    u16* __restrict__ ohi, u16* __restrict__ olo)
{
  __shared__ u16 sB[40 * 512];   // 40 KB per phase: 2 splits x 5 ks x 4 nt
  __shared__ float sfb[64];
  if (threadIdx.x < 64) sfb[threadIdx.x] = fb[threadIdx.x];

  int wid = threadIdx.x >> 6, lane = threadIdx.x & 63;
  long ib = ((long)blockIdx.x * 4 + wid) * 32;
  bool act = (ib < NVAR);
  int l15 = lane & 15, lg = lane >> 4;
  long node0 = 0, node1 = 0;
  if (act) { node0 = assoc[ib + l15]; node1 = assoc[ib + 16 + l15]; }

  const f32x4 z = {0.f, 0.f, 0.f, 0.f};
  f32x4 acc[2][4];
#pragma unroll
  for (int m = 0; m < 2; ++m)
#pragma unroll
    for (int n = 0; n < 4; ++n) acc[m][n] = z;

#pragma unroll 1
  for (int ph = 0; ph < 2; ++ph) {
    __syncthreads();
    for (int idx = threadIdx.x; idx < 160 * 64; idx += 256) {
      int k = idx >> 6, n = idx & 63;
      float w = fw[(size_t)(ph * 160 + k) * 64 + n];
      int ksp = k >> 5, nt = n >> 4;
      stage_frag(sB, (0 * 5 + ksp) * 4 + nt, (1 * 5 + ksp) * 4 + nt, k, n, w);
    }
    __syncthreads();
    if (!act) continue;
#pragma unroll
    for (int ks = 0; ks < 5; ++ks) {
      int kg = ph * 160 + ks * 32 + 8 * lg;
      int pl = kg >> 6, c = kg & 63;
      frag8 a0 = *reinterpret_cast<const frag8*>(xs + ((size_t)pl * NNODE + node0) * 64 + c);
      frag8 a1 = *reinterpret_cast<const frag8*>(xs + ((size_t)pl * NNODE + node1) * 64 + c);
#pragma unroll
      for (int n = 0; n < 4; ++n) {
        frag8 bh = *reinterpret_cast<const frag8*>(&sB[(((0 * 5 + ks) * 4 + n) * 512) + lane * 8]);
        frag8 bl = *reinterpret_cast<const frag8*>(&sB[(((1 * 5 + ks) * 4 + n) * 512) + lane * 8]);
        acc[0][n] = __builtin_amdgcn_mfma_f32_16x16x32_bf16(a0, bh, acc[0][n], 0, 0, 0);
        acc[0][n] = __builtin_amdgcn_mfma_f32_16x16x32_bf16(a0, bl, acc[0][n], 0, 0, 0);
        acc[1][n] = __builtin_amdgcn_mfma_f32_16x16x32_bf16(a1, bh, acc[1][n], 0, 0, 0);
        acc[1][n] = __builtin_amdgcn_mfma_f32_16x16x32_bf16(a1, bl, acc[1][n], 0, 0, 0);
      }
    }
  }
  if (!act) return;
#pragma unroll
  for (int m = 0; m < 2; ++m)
#pragma unroll
    for (int n = 0; n < 4; ++n)
#pragma unroll
      for (int r = 0; r < 4; ++r) {
        float v = fmaxf(acc[m][n][r] + sfb[n * 16 + l15], 0.f);
        u16 hi = f2bf(v);
        u16 lo = f2bf(v - bf2f(hi));
        size_t o = (size_t)(ib + 16 * m + 4 * lg + r) * 64 + n * 16 + l15;
        ohi[o] = hi; olo[o] = lo;
      }
}

// ---- head fc2/fc3: relu([NVAR,64]@[64,64]+b), hi/lo in+out, MFMA ---------
__global__ __launch_bounds__(256) void k_dense64(
    const u16* __restrict__ ahi, const u16* __restrict__ alo,
    const float* __restrict__ w, const float* __restrict__ b,
    u16* __restrict__ ohi, u16* __restrict__ olo)
{
  __shared__ u16 sB[16 * 512];   // 16 KB: 2 splits x 2 ks x 4 nt
  __shared__ float sbv[64];
  for (int idx = threadIdx.x; idx < 4096; idx += 256) {
    int k = idx >> 6, n = idx & 63;
    int ksp = k >> 5, nt = n >> 4;
    stage_frag(sB, (0 * 2 + ksp) * 4 + nt, (2 + ksp) * 4 + nt, k, n, w[idx]);
  }
  if (threadIdx.x < 64) sbv[threadIdx.x] = b[threadIdx.x];
  __syncthreads();

  int wid = threadIdx.x >> 6, lane = threadIdx.x & 63;
  long ib = ((long)blockIdx.x * 4 + wid) * 32;
  if (ib >= NVAR) return;
  int l15 = lane & 15, lg = lane >> 4;

  const f32x4 z = {0.f, 0.f, 0.f, 0.f};
  f32x4 acc[2][4];
#pragma unroll
  for (int m = 0; m < 2; ++m)
#pragma unroll
    for (int n = 0; n < 4; ++n) acc[m][n] = z;

  const u16* r0 = (const u16*)(ahi + (ib + l15) * 64 + 8 * lg);
  const u16* r1 = r0 + 16 * 64;
  const u16* s0 = (const u16*)(alo + (ib + l15) * 64 + 8 * lg);
  const u16* s1 = s0 + 16 * 64;
#pragma unroll
  for (int ks = 0; ks < 2; ++ks) {
    frag8 ah0 = *reinterpret_cast<const frag8*>(r0 + ks * 32);
    frag8 ah1 = *reinterpret_cast<const frag8*>(r1 + ks * 32);
    frag8 al0 = *reinterpret_cast<const frag8*>(s0 + ks * 32);
    frag8 al1 = *reinterpret_cast<const frag8*>(s1 + ks * 32);
#pragma unroll
    for (int n = 0; n < 4; ++n) {
      frag8 bh = *reinterpret_cast<const frag8*>(&sB[(((0 * 2 + ks) * 4 + n) * 512) + lane * 8]);
      frag8 bl = *reinterpret_cast<const frag8*>(&sB[(((2 + ks) * 4 + n) * 512) + lane * 8]);
      acc[0][n] = __builtin_amdgcn_mfma_f32_16x16x32_bf16(ah0, bh, acc[0][n], 0, 0, 0);
      acc[0][n] = __builtin_amdgcn_mfma_f32_16x16x32_bf16(al0, bh, acc[0][n], 0, 0, 0);
      acc[0][n] = __builtin_amdgcn_mfma_f32_16x16x32_bf16(ah0, bl, acc[0][n], 0, 0, 0);
      acc[1][n] = __builtin_amdgcn_mfma_f32_16x16x32_bf16(ah1, bh, acc[1][n], 0, 0, 0);
      acc[1][n] = __builtin_amdgcn_mfma_f32_16x16x32_bf16(al1, bh, acc[1][n], 0, 0, 0);
      acc[1][n] = __builtin_amdgcn_mfma_f32_16x16x32_bf16(ah1, bl, acc[1][n], 0, 0, 0);
    }
  }
#pragma unroll
  for (int m = 0; m < 2; ++m)
#pragma unroll
    for (int n = 0; n < 4; ++n)
#pragma unroll
      for (int r = 0; r < 4; ++r) {
        float v = fmaxf(acc[m][n][r] + sbv[n * 16 + l15], 0.f);
        u16 hi = f2bf(v);
        u16 lo = f2bf(v - bf2f(hi));
        size_t o = (size_t)(ib + 16 * m + 4 * lg + r) * 64 + n * 16 + l15;
        ohi[o] = hi; olo[o] = lo;
      }
}

// ---- head fc4: dot + bias -> out (hi/lo input) ---------------------------
__global__ __launch_bounds__(256) void k_head4(
    const u16* __restrict__ ahi, const u16* __restrict__ alo,
    const float* __restrict__ w, const float* __restrict__ b,
    float* __restrict__ out)
{
  __shared__ float sw[64];
  if (threadIdx.x < 64) sw[threadIdx.x] = w[threadIdx.x];
  __syncthreads();
  int i = blockIdx.x * 256 + threadIdx.x;
  if (i >= NVAR) return;
  float acc = b[0];
  const uint4* hp = reinterpret_cast<const uint4*>(ahi + (size_t)i * 64);
  const uint4* lp = reinterpret_cast<const uint4*>(alo + (size_t)i * 64);
#pragma unroll
  for (int j = 0; j < 8; ++j) {
    uint4 h = hp[j], l = lp[j];
    acc += (cvlo(h.x) + cvlo(l.x)) * sw[8 * j + 0] + (cvhi(h.x) + cvhi(l.x)) * sw[8 * j + 1];
    acc += (cvlo(h.y) + cvlo(l.y)) * sw[8 * j + 2] + (cvhi(h.y) + cvhi(l.y)) * sw[8 * j + 3];
    acc += (cvlo(h.z) + cvlo(l.z)) * sw[8 * j + 4] + (cvhi(h.z) + cvhi(l.z)) * sw[8 * j + 5];
    acc += (cvlo(h.w) + cvlo(l.w)) * sw[8 * j + 6] + (cvhi(h.w) + cvhi(l.w)) * sw[8 * j + 7];
  }
  out[i] = acc;
}

// ---- launch --------------------------------------------------------------
extern "C" void kernel_launch(void* const* d_in, const int* in_sizes, int n_in,
                              void* d_out, int out_size, void* d_ws, size_t ws_size,
                              hipStream_t stream)
{
  (void)in_sizes; (void)n_in; (void)out_size; (void)ws_size;
  const float* var_nf = (const float*)d_in[0];
  const float* con_nf = (const float*)d_in[1];
  const float* edge_f = (const float*)d_in[2];
  const int*   eidx   = (const int*)d_in[3];
  const int*   etyp   = (const int*)d_in[4];
  const int*   avar   = (const int*)d_in[5];
  const int*   acon   = (const int*)d_in[6];
  const float* vw1 = (const float*)d_in[7];
  const float* vb1 = (const float*)d_in[8];
  const float* vw2 = (const float*)d_in[9];
  const float* vb2 = (const float*)d_in[10];
  const float* cw1 = (const float*)d_in[11];
  const float* cb1 = (const float*)d_in[12];
  const float* cw2 = (const float*)d_in[13];
  const float* cb2 = (const float*)d_in[14];
  const float* hw1 = (const float*)d_in[15];
  const float* hb1 = (const float*)d_in[16];
  const float* hw2 = (const float*)d_in[17];
  const float* hb2 = (const float*)d_in[18];
  const float* wco = (const float*)d_in[19];
  const float* wva = (const float*)d_in[20];
  const float* bia = (const float*)d_in[21];
  const float* f1w = (const float*)d_in[22];
  const float* f1b = (const float*)d_in[23];
  const float* f2w = (const float*)d_in[24];
  const float* f2b = (const float*)d_in[25];
  const float* f3w = (const float*)d_in[26];
  const float* f3b = (const float*)d_in[27];
  const float* f4w = (const float*)d_in[28];
  const float* f4b = (const float*)d_in[29];

  char* ws = (char*)d_ws;
  // xs [0,64M) | tbl [64M,115.2M) | cnt [115.2M,115.6M) | slots [115.6M,128.4M)
  // head hi/lo planes overlay the tbl region (dead after the 4 layers).
  u16*   xs    = (u16*)ws;
  float* tbl   = (float*)(ws + 64000000);
  int*   cnt   = (int*)(ws + 115200000);
  int*   slots = (int*)(ws + 115600000);
  u16* hAhi = (u16*)(ws + 64000000);
  u16* hAlo = (u16*)(ws + 71680000);
  u16* hBhi = (u16*)(ws + 79360000);
  u16* hBlo = (u16*)(ws + 87040000);

  const int* esrc = eidx;
  const int* edst = eidx + NEDGE;

  k_var_init<<<(NVAR + 255) / 256, 256, 0, stream>>>(var_nf, avar, vw1, vb1, vw2, vb2, xs);
  k_con_init<<<(NCON + 255) / 256, 256, 0, stream>>>(con_nf, acon, cw1, cb1, cw2, cb2, xs);
  hipMemsetAsync(cnt, 0, NNODE * sizeof(int), stream);
  k_scatter<<<(NEDGE + 255) / 256, 256, 0, stream>>>(esrc, edst, etyp, cnt, slots);

  for (int l = 0; l < 4; ++l) {
    u16* xin  = xs + (size_t)l * NNODE * 64;
    u16* xout = xs + (size_t)(l + 1) * NNODE * 64;
    k_node<<<(NNODE + 127) / 128, 256, 0, stream>>>(
        xin, edge_f,
        hw1 + l * 4096, hb1 + l * 64, hw2 + l * 64, hb2 + l,
        wco + l * 3844, wva + l * 4096, tbl);
    k_aggr<<<NNODE / 4, 256, 0, stream>>>(tbl, cnt, slots, bia + l * 64, xout);
  }

  k_head1<<<(NVAR + 127) / 128, 256, 0, stream>>>(xs, avar, f1w, f1b, hAhi, hAlo);
  k_dense64<<<(NVAR + 127) / 128, 256, 0, stream>>>(hAhi, hAlo, f2w, f2b, hBhi, hBlo);
  k_dense64<<<(NVAR + 127) / 128, 256, 0, stream>>>(hBhi, hBlo, f3w, f3b, hAhi, hAlo);
  k_head4<<<(NVAR + 255) / 256, 256, 0, stream>>>(hAhi, hAlo, f4w, f4b, (float*)d_out);
}

// Round 5
// 428.310 us; speedup vs baseline: 16.7365x; 1.6717x over previous
//
#include <hip/hip_runtime.h>
#include <hip/hip_bf16.h>

typedef unsigned int u32;
typedef unsigned short u16;
typedef __attribute__((ext_vector_type(8))) short frag8;   // 8 bf16 (4 VGPRs)
typedef __attribute__((ext_vector_type(4))) float f32x4;   // MFMA C/D

#define NNODE 100000
#define NVAR  60000
#define NCON  40000
#define NEDGE 500000
#define SLOTCAP 32
#define TBL1 6400000UL
#define VAR_BLOCKS 469   // ceil(60000/128)
#define CON_BLOCKS 313   // ceil(40000/128)

// prep-region offsets (u16 units) within wp
#define WP_NODE(l)  ((l) * 24576)        // 4 x 48KB frag images
#define WP_VARW2    98304
#define WP_CONW2    106496
#define WP_FC1(ph)  (114688 + (ph) * 20480)
#define WP_FC2      155648
#define WP_FC3      163840
#define PREP_TOTAL  86016                // elements staged by k_prep

// ---- helpers -------------------------------------------------------------
__device__ __forceinline__ u16 f2bf(float f) {
  u32 u = __float_as_uint(f);
  u32 r = (u + 0x7fffu + ((u >> 16) & 1u)) >> 16;   // RNE
  return (u16)r;
}
__device__ __forceinline__ float bf2f(u16 u) { return __uint_as_float(((u32)u) << 16); }
__device__ __forceinline__ float cvlo(u32 p) { return __uint_as_float(p << 16); }
__device__ __forceinline__ float cvhi(u32 p) { return __uint_as_float(p & 0xffff0000u); }
__device__ __forceinline__ float sigmoidf_(float x) {
  return __builtin_amdgcn_rcpf(1.0f + __expf(-x));
}

// ---- k_prep: format all weight matrices into hi/lo MFMA fragment images --
// frag image layout: frag*512 + lane*8 + j  (lane = (n&15)|(((k&31)>>3)<<4), j=k&7)
__global__ __launch_bounds__(256) void k_prep(
    const float* __restrict__ hw1, const float* __restrict__ wco,
    const float* __restrict__ wva, const float* __restrict__ vw2,
    const float* __restrict__ cw2, const float* __restrict__ f1w,
    const float* __restrict__ f2w, const float* __restrict__ f3w,
    u16* __restrict__ wp)
{
  int g = blockIdx.x * 256 + threadIdx.x;
  if (g >= PREP_TOTAL) return;
  float w; u16* base; int k, n, fr_hi, fr_lo;
  if (g < 49152) {                               // node mats: 4 layers x 3 x 4096
    int l = g / 12288, e = g % 12288;
    int mat = e >> 12, idx = e & 4095;
    k = idx >> 6; n = idx & 63;
    if (mat == 0) w = hw1[l * 4096 + idx];
    else if (mat == 1) w = (k < 62 && n < 62) ? wco[l * 3844 + k * 62 + n] : 0.f;
    else w = wva[l * 4096 + idx];
    base = wp + WP_NODE(l);
    int ksp = k >> 5, nt = n >> 4;
    fr_hi = ((mat * 2 + 0) * 2 + ksp) * 4 + nt;
    fr_lo = ((mat * 2 + 1) * 2 + ksp) * 4 + nt;
  } else if (g < 53248) {                        // var w2 (62x62 padded)
    int idx = g - 49152; k = idx >> 6; n = idx & 63;
    w = (k < 62 && n < 62) ? vw2[k * 62 + n] : 0.f;
    base = wp + WP_VARW2;
    int ksp = k >> 5, nt = n >> 4;
    fr_hi = ksp * 4 + nt; fr_lo = (2 + ksp) * 4 + nt;
  } else if (g < 57344) {                        // con w2 (63x63 padded)
    int idx = g - 53248; k = idx >> 6; n = idx & 63;
    w = (k < 63 && n < 63) ? cw2[k * 63 + n] : 0.f;
    base = wp + WP_CONW2;
    int ksp = k >> 5, nt = n >> 4;
    fr_hi = ksp * 4 + nt; fr_lo = (2 + ksp) * 4 + nt;
  } else if (g < 77824) {                        // fc1 (320x64), 2 phases
    int e = g - 57344; int kk = e >> 6; n = e & 63;
    int ph = (kk >= 160); k = kk - ph * 160;
    w = f1w[(size_t)kk * 64 + n];
    base = wp + WP_FC1(ph);
    int ksp = k >> 5, nt = n >> 4;
    fr_hi = ksp * 4 + nt; fr_lo = (5 + ksp) * 4 + nt;
  } else if (g < 81920) {                        // fc2 (64x64)
    int idx = g - 77824; k = idx >> 6; n = idx & 63;
    w = f2w[idx];
    base = wp + WP_FC2;
    int ksp = k >> 5, nt = n >> 4;
    fr_hi = ksp * 4 + nt; fr_lo = (2 + ksp) * 4 + nt;
  } else {                                       // fc3 (64x64)
    int idx = g - 81920; k = idx >> 6; n = idx & 63;
    w = f3w[idx];
    base = wp + WP_FC3;
    int ksp = k >> 5, nt = n >> 4;
    fr_hi = ksp * 4 + nt; fr_lo = (2 + ksp) * 4 + nt;
  }
  u16 hi = f2bf(w);
  u16 lo = f2bf(w - bf2f(hi));
  int lane = (n & 15) | (((k & 31) >> 3) << 4);
  int j = k & 7;
  base[fr_hi * 512 + lane * 8 + j] = hi;
  base[fr_lo * 512 + lane * 8 + j] = lo;
}

// ---- fused var+con init (MFMA, transposed) + cnt zeroing -----------------
__global__ __launch_bounds__(256) void k_init(
    const float* __restrict__ vf, const float* __restrict__ cf,
    const int* __restrict__ avar, const int* __restrict__ acon,
    const float* __restrict__ vw1, const float* __restrict__ vb1, const float* __restrict__ vb2,
    const float* __restrict__ cw1, const float* __restrict__ cb1, const float* __restrict__ cb2,
    const u16* __restrict__ wp, u16* __restrict__ x0, int* __restrict__ cnt)
{
  for (int i = blockIdx.x * 256 + threadIdx.x; i < NNODE; i += gridDim.x * 256) cnt[i] = 0;

  const bool isVar = blockIdx.x < VAR_BLOCKS;
  const int bbase = isVar ? blockIdx.x : (blockIdx.x - VAR_BLOCKS);
  const int nItems = isVar ? NVAR : NCON;
  const int KD = isVar ? 62 : 63;
  const float* in  = isVar ? vf : cf;
  const int*   asc = isVar ? avar : acon;
  const float* w1  = isVar ? vw1 : cw1;
  const float* b1  = isVar ? vb1 : cb1;
  const float* b2  = isVar ? vb2 : cb2;
  const u16*   src = wp + (isVar ? WP_VARW2 : WP_CONW2);

  __shared__ u16 sB[16 * 512];
  __shared__ float sw1[64], sb1[64], sb2[64];
  {
    const uint4* s4 = reinterpret_cast<const uint4*>(src);
    uint4* d4 = reinterpret_cast<uint4*>(sB);
    for (int i = threadIdx.x; i < 1024; i += 256) d4[i] = s4[i];
  }
  if (threadIdx.x < 64) {
    int t = threadIdx.x;
    sw1[t] = (t < KD) ? w1[t] : 0.f;
    sb1[t] = (t < KD) ? b1[t] : 0.f;
    sb2[t] = (t < KD) ? b2[t] : 0.f;
  }
  __syncthreads();

  int wid = threadIdx.x >> 6, lane = threadIdx.x & 63;
  long ib = ((long)bbase * 4 + wid) * 32;
  if (ib >= nItems) return;
  int l15 = lane & 15, lg = lane >> 4;

  float w1r[16], b1r[16];
#pragma unroll
  for (int ks = 0; ks < 2; ++ks)
#pragma unroll
    for (int j = 0; j < 8; ++j) {
      int k = 32 * ks + 8 * lg + j;
      w1r[ks * 8 + j] = sw1[k]; b1r[ks * 8 + j] = sb1[k];
    }

  float v0 = in[ib + l15], v1 = in[ib + 16 + l15];
  frag8 hh[2][2], hl[2][2];
#pragma unroll
  for (int np = 0; np < 2; ++np) {
    float v = np ? v1 : v0;
#pragma unroll
    for (int ks = 0; ks < 2; ++ks) {
      frag8 th, tl;
#pragma unroll
      for (int j = 0; j < 8; ++j) {
        float h = fmaxf(fmaf(v, w1r[ks * 8 + j], b1r[ks * 8 + j]), 0.f);
        u16 hi = f2bf(h);
        u16 lo = f2bf(h - bf2f(hi));
        th[j] = (short)hi; tl[j] = (short)lo;
      }
      hh[np][ks] = th; hl[np][ks] = tl;
    }
  }

  const f32x4 z = {0.f, 0.f, 0.f, 0.f};
  f32x4 acc[4][2];
#pragma unroll
  for (int m = 0; m < 4; ++m)
#pragma unroll
    for (int np = 0; np < 2; ++np) acc[m][np] = z;

#pragma unroll
  for (int ks = 0; ks < 2; ++ks)
#pragma unroll
    for (int m = 0; m < 4; ++m) {
      frag8 bh = *reinterpret_cast<const frag8*>(&sB[((ks * 4 + m) * 512) + lane * 8]);
      frag8 bl = *reinterpret_cast<const frag8*>(&sB[(((2 + ks) * 4 + m) * 512) + lane * 8]);
#pragma unroll
      for (int np = 0; np < 2; ++np) {
        acc[m][np] = __builtin_amdgcn_mfma_f32_16x16x32_bf16(bh, hh[np][ks], acc[m][np], 0, 0, 0);
        acc[m][np] = __builtin_amdgcn_mfma_f32_16x16x32_bf16(bh, hl[np][ks], acc[m][np], 0, 0, 0);
        acc[m][np] = __builtin_amdgcn_mfma_f32_16x16x32_bf16(bl, hh[np][ks], acc[m][np], 0, 0, 0);
      }
    }

#pragma unroll
  for (int np = 0; np < 2; ++np) {
    long r = asc[ib + 16 * np + l15];
    float vv = np ? v1 : v0;
    u16* orow = x0 + r * 64;
#pragma unroll
    for (int m = 0; m < 4; ++m) {
      float o[4];
#pragma unroll
      for (int rr = 0; rr < 4; ++rr) o[rr] = acc[m][np][rr] + sb2[16 * m + 4 * lg + rr];
      if (m == 3 && lg == 3) {
        if (isVar) { o[2] = vv; o[3] = 1.0f; } else { o[3] = vv; }
      }
      u32 p0 = (u32)f2bf(o[0]) | ((u32)f2bf(o[1]) << 16);
      u32 p1 = (u32)f2bf(o[2]) | ((u32)f2bf(o[3]) << 16);
      *reinterpret_cast<uint2*>(orow + 16 * m + 4 * lg) = make_uint2(p0, p1);
    }
  }
}

// ---- CSR-ish bucket build: slots[d][pos] = src | (type<<20) --------------
__global__ __launch_bounds__(256) void k_scatter(
    const int* __restrict__ src, const int* __restrict__ dst,
    const int* __restrict__ et, int* __restrict__ cnt, int* __restrict__ slots)
{
  int e = blockIdx.x * 256 + threadIdx.x;
  if (e >= NEDGE) return;
  int d = dst[e];
  int pos = atomicAdd(&cnt[d], 1);
  if (pos < SLOTCAP) slots[d * SLOTCAP + pos] = src[e] | ((et[e] & 1) << 20);
}

// ---- per-layer NODE table kernel (transposed MFMA, float4 epilogue) ------
__global__ __launch_bounds__(256) void k_node(
    const u16* __restrict__ x, const float* __restrict__ ef,
    const u16* __restrict__ wsrc, const float* __restrict__ b1,
    const float* __restrict__ w2, const float* __restrict__ b2,
    float* __restrict__ tbl)
{
  __shared__ u16 sB[48 * 512];
  __shared__ float sb1[64], sw2[64];
  {
    const uint4* s4 = reinterpret_cast<const uint4*>(wsrc);
    uint4* d4 = reinterpret_cast<uint4*>(sB);
    for (int i = threadIdx.x; i < 3072; i += 256) d4[i] = s4[i];
  }
  if (threadIdx.x < 64) { sb1[threadIdx.x] = b1[threadIdx.x]; sw2[threadIdx.x] = w2[threadIdx.x]; }
  __syncthreads();

  int wid = threadIdx.x >> 6, lane = threadIdx.x & 63;
  long nb = ((long)blockIdx.x * 4 + wid) * 32;
  if (nb >= NNODE) return;
  int l15 = lane & 15, lg = lane >> 4;

  frag8 xf[2][2];
#pragma unroll
  for (int np = 0; np < 2; ++np) {
    const u16* base = x + (nb + 16 * np + l15) * 64 + 8 * lg;
    xf[np][0] = *reinterpret_cast<const frag8*>(base);
    xf[np][1] = *reinterpret_cast<const frag8*>(base + 32);
  }

  const f32x4 z = {0.f, 0.f, 0.f, 0.f};
  f32x4 acc[3][4][2];
#pragma unroll
  for (int a = 0; a < 3; ++a)
#pragma unroll
    for (int m = 0; m < 4; ++m)
#pragma unroll
      for (int np = 0; np < 2; ++np) acc[a][m][np] = z;

#pragma unroll
  for (int ks = 0; ks < 2; ++ks)
#pragma unroll
    for (int mat = 0; mat < 3; ++mat)
#pragma unroll
      for (int m = 0; m < 4; ++m) {
        frag8 bh = *reinterpret_cast<const frag8*>(
            &sB[((((mat * 2 + 0) * 2 + ks) * 4 + m) * 512) + lane * 8]);
        frag8 bl = *reinterpret_cast<const frag8*>(
            &sB[((((mat * 2 + 1) * 2 + ks) * 4 + m) * 512) + lane * 8]);
#pragma unroll
        for (int np = 0; np < 2; ++np) {
          acc[mat][m][np] = __builtin_amdgcn_mfma_f32_16x16x32_bf16(bh, xf[np][ks], acc[mat][m][np], 0, 0, 0);
          acc[mat][m][np] = __builtin_amdgcn_mfma_f32_16x16x32_bf16(bl, xf[np][ks], acc[mat][m][np], 0, 0, 0);
        }
      }

  float b2v = b2[0];
#pragma unroll
  for (int np = 0; np < 2; ++np) {
    float p = 0.f;
#pragma unroll
    for (int m = 0; m < 4; ++m)
#pragma unroll
      for (int r = 0; r < 4; ++r)
        p += sigmoidf_(acc[0][m][np][r] + sb1[16 * m + 4 * lg + r]) * sw2[16 * m + 4 * lg + r];
    p += __shfl_xor(p, 16);
    p += __shfl_xor(p, 32);
    long node = nb + 16 * np + l15;
    float va = (p + b2v) * ef[node];
    float x62 = bf2f((u16)(short)xf[np][1][6]);   // k = 32+8*3+6 = 62 (valid at lg==3)
    float* t0 = tbl + node * 64;
    float* t1 = tbl + TBL1 + node * 64;
#pragma unroll
    for (int m = 0; m < 4; ++m) {
      f32x4 o = acc[1][m][np];
      if (m == 3 && lg == 3) { o[2] = x62; o[3] = va; }
      *reinterpret_cast<f32x4*>(t0 + 16 * m + 4 * lg) = o;
      *reinterpret_cast<f32x4*>(t1 + 16 * m + 4 * lg) = acc[2][m][np];
    }
  }
}

// ---- aggregation: wave/node, 4 slots in parallel (16-lane quarters) ------
__global__ __launch_bounds__(256) void k_aggr(
    const float* __restrict__ tbl, const int* __restrict__ cnt,
    const int* __restrict__ slots, const float* __restrict__ bias,
    u16* __restrict__ xout)
{
  int wid = threadIdx.x >> 6, lane = threadIdx.x & 63;
  int q = lane >> 4, p = lane & 15;
  int n = blockIdx.x * 4 + wid;            // grid = 25000 blocks exactly
  int deg = cnt[n]; if (deg > SLOTCAP) deg = SLOTCAP;
  const int* sl = slots + (size_t)n * SLOTCAP;
  f32x4 acc = {0.f, 0.f, 0.f, 0.f};
#pragma unroll 1
  for (int j0 = 0; j0 < deg; j0 += 4) {
    int j = j0 + q;
    if (j < deg) {
      int v = sl[j];
      int s = v & 0xFFFFF, t = v >> 20;
      acc += *reinterpret_cast<const f32x4*>(tbl + ((size_t)t * NNODE + s) * 64 + p * 4);
    }
  }
#pragma unroll
  for (int c = 0; c < 4; ++c) {
    acc[c] += __shfl_xor(acc[c], 16);
    acc[c] += __shfl_xor(acc[c], 32);
  }
  f32x4 bv = *reinterpret_cast<const f32x4*>(bias + p * 4);
  if (q == 0) {
    u32 w0 = (u32)f2bf(fmaxf(acc[0] + bv[0], 0.f)) | ((u32)f2bf(fmaxf(acc[1] + bv[1], 0.f)) << 16);
    u32 w1 = (u32)f2bf(fmaxf(acc[2] + bv[2], 0.f)) | ((u32)f2bf(fmaxf(acc[3] + bv[3], 0.f)) << 16);
    *reinterpret_cast<uint2*>(xout + (size_t)n * 64 + p * 4) = make_uint2(w0, w1);
  }
}

// ---- head fc1: [NVAR,320]@[320,64] transposed MFMA, 2 LDS phases ---------
__global__ __launch_bounds__(256) void k_head1(
    const u16* __restrict__ xs, const int* __restrict__ assoc,
    const u16* __restrict__ wp, const float* __restrict__ fb,
    u16* __restrict__ ohi, u16* __restrict__ olo)
{
  __shared__ u16 sB[40 * 512];
  __shared__ float sfb[64];
  if (threadIdx.x < 64) sfb[threadIdx.x] = fb[threadIdx.x];

  int wid = threadIdx.x >> 6, lane = threadIdx.x & 63;
  long ib = ((long)blockIdx.x * 4 + wid) * 32;
  bool act = (ib < NVAR);
  int l15 = lane & 15, lg = lane >> 4;
  long node0 = 0, node1 = 0;
  if (act) { node0 = assoc[ib + l15]; node1 = assoc[ib + 16 + l15]; }

  const f32x4 z = {0.f, 0.f, 0.f, 0.f};
  f32x4 acc[4][2];
#pragma unroll
  for (int m = 0; m < 4; ++m)
#pragma unroll
    for (int np = 0; np < 2; ++np) acc[m][np] = z;

#pragma unroll 1
  for (int ph = 0; ph < 2; ++ph) {
    __syncthreads();
    {
      const uint4* s4 = reinterpret_cast<const uint4*>(wp + WP_FC1(ph));
      uint4* d4 = reinterpret_cast<uint4*>(sB);
      for (int i = threadIdx.x; i < 2560; i += 256) d4[i] = s4[i];
    }
    __syncthreads();
    if (!act) continue;
#pragma unroll
    for (int ks = 0; ks < 5; ++ks) {
      int kg = ph * 160 + ks * 32;
      int pl = kg >> 6, c = (kg & 63) + 8 * lg;
      frag8 a0 = *reinterpret_cast<const frag8*>(xs + ((size_t)pl * NNODE + node0) * 64 + c);
      frag8 a1 = *reinterpret_cast<const frag8*>(xs + ((size_t)pl * NNODE + node1) * 64 + c);
#pragma unroll
      for (int m = 0; m < 4; ++m) {
        frag8 bh = *reinterpret_cast<const frag8*>(&sB[((ks * 4 + m) * 512) + lane * 8]);
        frag8 bl = *reinterpret_cast<const frag8*>(&sB[(((5 + ks) * 4 + m) * 512) + lane * 8]);
        acc[m][0] = __builtin_amdgcn_mfma_f32_16x16x32_bf16(bh, a0, acc[m][0], 0, 0, 0);
        acc[m][0] = __builtin_amdgcn_mfma_f32_16x16x32_bf16(bl, a0, acc[m][0], 0, 0, 0);
        acc[m][1] = __builtin_amdgcn_mfma_f32_16x16x32_bf16(bh, a1, acc[m][1], 0, 0, 0);
        acc[m][1] = __builtin_amdgcn_mfma_f32_16x16x32_bf16(bl, a1, acc[m][1], 0, 0, 0);
      }
    }
  }
  if (!act) return;
#pragma unroll
  for (int np = 0; np < 2; ++np) {
    size_t row = (size_t)(ib + 16 * np + l15) * 64;
#pragma unroll
    for (int m = 0; m < 4; ++m) {
      u16 hi[4], lo[4];
#pragma unroll
      for (int r = 0; r < 4; ++r) {
        float v = fmaxf(acc[m][np][r] + sfb[16 * m + 4 * lg + r], 0.f);
        hi[r] = f2bf(v);
        lo[r] = f2bf(v - bf2f(hi[r]));
      }
      size_t o = row + 16 * m + 4 * lg;
      *reinterpret_cast<uint2*>(ohi + o) =
          make_uint2((u32)hi[0] | ((u32)hi[1] << 16), (u32)hi[2] | ((u32)hi[3] << 16));
      *reinterpret_cast<uint2*>(olo + o) =
          make_uint2((u32)lo[0] | ((u32)lo[1] << 16), (u32)lo[2] | ((u32)lo[3] << 16));
    }
  }
}

// ---- head fc2/fc3: relu([NVAR,64]@[64,64]+b), transposed MFMA ------------
__global__ __launch_bounds__(256) void k_dense64(
    const u16* __restrict__ ahi, const u16* __restrict__ alo,
    const u16* __restrict__ wsrc, const float* __restrict__ b,
    u16* __restrict__ ohi, u16* __restrict__ olo)
{
  __shared__ u16 sB[16 * 512];
  __shared__ float sbv[64];
  {
    const uint4* s4 = reinterpret_cast<const uint4*>(wsrc);
    uint4* d4 = reinterpret_cast<uint4*>(sB);
    for (int i = threadIdx.x; i < 1024; i += 256) d4[i] = s4[i];
  }
  if (threadIdx.x < 64) sbv[threadIdx.x] = b[threadIdx.x];
  __syncthreads();

  int wid = threadIdx.x >> 6, lane = threadIdx.x & 63;
  long ib = ((long)blockIdx.x * 4 + wid) * 32;
  if (ib >= NVAR) return;
  int l15 = lane & 15, lg = lane >> 4;

  frag8 xh[2][2], xl[2][2];
#pragma unroll
  for (int np = 0; np < 2; ++np) {
    const u16* bh_ = ahi + (ib + 16 * np + l15) * 64 + 8 * lg;
    const u16* bl_ = alo + (ib + 16 * np + l15) * 64 + 8 * lg;
    xh[np][0] = *reinterpret_cast<const frag8*>(bh_);
    xh[np][1] = *reinterpret_cast<const frag8*>(bh_ + 32);
    xl[np][0] = *reinterpret_cast<const frag8*>(bl_);
    xl[np][1] = *reinterpret_cast<const frag8*>(bl_ + 32);
  }

  const f32x4 z = {0.f, 0.f, 0.f, 0.f};
  f32x4 acc[4][2];
#pragma unroll
  for (int m = 0; m < 4; ++m)
#pragma unroll
    for (int np = 0; np < 2; ++np) acc[m][np] = z;

#pragma unroll
  for (int ks = 0; ks < 2; ++ks)
#pragma unroll
    for (int m = 0; m < 4; ++m) {
      frag8 bh = *reinterpret_cast<const frag8*>(&sB[((ks * 4 + m) * 512) + lane * 8]);
      frag8 bl = *reinterpret_cast<const frag8*>(&sB[(((2 + ks) * 4 + m) * 512) + lane * 8]);
#pragma unroll
      for (int np = 0; np < 2; ++np) {
        acc[m][np] = __builtin_amdgcn_mfma_f32_16x16x32_bf16(bh, xh[np][ks], acc[m][np], 0, 0, 0);
        acc[m][np] = __builtin_amdgcn_mfma_f32_16x16x32_bf16(bh, xl[np][ks], acc[m][np], 0, 0, 0);
        acc[m][np] = __builtin_amdgcn_mfma_f32_16x16x32_bf16(bl, xh[np][ks], acc[m][np], 0, 0, 0);
      }
    }

#pragma unroll
  for (int np = 0; np < 2; ++np) {
    size_t row = (size_t)(ib + 16 * np + l15) * 64;
#pragma unroll
    for (int m = 0; m < 4; ++m) {
      u16 hi[4], lo[4];
#pragma unroll
      for (int r = 0; r < 4; ++r) {
        float v = fmaxf(acc[m][np][r] + sbv[16 * m + 4 * lg + r], 0.f);
        hi[r] = f2bf(v);
        lo[r] = f2bf(v - bf2f(hi[r]));
      }
      size_t o = row + 16 * m + 4 * lg;
      *reinterpret_cast<uint2*>(ohi + o) =
          make_uint2((u32)hi[0] | ((u32)hi[1] << 16), (u32)hi[2] | ((u32)hi[3] << 16));
      *reinterpret_cast<uint2*>(olo + o) =
          make_uint2((u32)lo[0] | ((u32)lo[1] << 16), (u32)lo[2] | ((u32)lo[3] << 16));
    }
  }
}

// ---- head fc4: dot + bias -> out (hi/lo input) ---------------------------
__global__ __launch_bounds__(256) void k_head4(
    const u16* __restrict__ ahi, const u16* __restrict__ alo,
    const float* __restrict__ w, const float* __restrict__ b,
    float* __restrict__ out)
{
  __shared__ float sw[64];
  if (threadIdx.x < 64) sw[threadIdx.x] = w[threadIdx.x];
  __syncthreads();
  int i = blockIdx.x * 256 + threadIdx.x;
  if (i >= NVAR) return;
  float acc = b[0];
  const uint4* hp = reinterpret_cast<const uint4*>(ahi + (size_t)i * 64);
  const uint4* lp = reinterpret_cast<const uint4*>(alo + (size_t)i * 64);
#pragma unroll
  for (int j = 0; j < 8; ++j) {
    uint4 h = hp[j], l = lp[j];
    acc += (cvlo(h.x) + cvlo(l.x)) * sw[8 * j + 0] + (cvhi(h.x) + cvhi(l.x)) * sw[8 * j + 1];
    acc += (cvlo(h.y) + cvlo(l.y)) * sw[8 * j + 2] + (cvhi(h.y) + cvhi(l.y)) * sw[8 * j + 3];
    acc += (cvlo(h.z) + cvlo(l.z)) * sw[8 * j + 4] + (cvhi(h.z) + cvhi(l.z)) * sw[8 * j + 5];
    acc += (cvlo(h.w) + cvlo(l.w)) * sw[8 * j + 6] + (cvhi(h.w) + cvhi(l.w)) * sw[8 * j + 7];
  }
  out[i] = acc;
}

// ---- launch --------------------------------------------------------------
extern "C" void kernel_launch(void* const* d_in, const int* in_sizes, int n_in,
                              void* d_out, int out_size, void* d_ws, size_t ws_size,
                              hipStream_t stream)
{
  (void)in_sizes; (void)n_in; (void)out_size; (void)ws_size;
  const float* var_nf = (const float*)d_in[0];
  const float* con_nf = (const float*)d_in[1];
  const float* edge_f = (const float*)d_in[2];
  const int*   eidx   = (const int*)d_in[3];
  const int*   etyp   = (const int*)d_in[4];
  const int*   avar   = (const int*)d_in[5];
  const int*   acon   = (const int*)d_in[6];
  const float* vw1 = (const float*)d_in[7];
  const float* vb1 = (const float*)d_in[8];
  const float* vw2 = (const float*)d_in[9];
  const float* vb2 = (const float*)d_in[10];
  const float* cw1 = (const float*)d_in[11];
  const float* cb1 = (const float*)d_in[12];
  const float* cw2 = (const float*)d_in[13];
  const float* cb2 = (const float*)d_in[14];
  const float* hw1 = (const float*)d_in[15];
  const float* hb1 = (const float*)d_in[16];
  const float* hw2 = (const float*)d_in[17];
  const float* hb2 = (const float*)d_in[18];
  const float* wco = (const float*)d_in[19];
  const float* wva = (const float*)d_in[20];
  const float* bia = (const float*)d_in[21];
  const float* f1w = (const float*)d_in[22];
  const float* f1b = (const float*)d_in[23];
  const float* f2w = (const float*)d_in[24];
  const float* f2b = (const float*)d_in[25];
  const float* f3w = (const float*)d_in[26];
  const float* f3b = (const float*)d_in[27];
  const float* f4w = (const float*)d_in[28];
  const float* f4b = (const float*)d_in[29];

  char* ws = (char*)d_ws;
  // xs [0,64M) | tbl [64M,115.2M) | cnt [115.2M,115.6M) | slots [115.6M,128.4M)
  // | wprep [128.4M, +344KB). Head hi/lo planes overlay the tbl region.
  u16*   xs    = (u16*)ws;
  float* tbl   = (float*)(ws + 64000000);
  int*   cnt   = (int*)(ws + 115200000);
  int*   slots = (int*)(ws + 115600000);
  u16*   wp    = (u16*)(ws + 128400000);
  u16* hAhi = (u16*)(ws + 64000000);
  u16* hAlo = (u16*)(ws + 71680000);
  u16* hBhi = (u16*)(ws + 79360000);
  u16* hBlo = (u16*)(ws + 87040000);

  const int* esrc = eidx;
  const int* edst = eidx + NEDGE;

  k_prep<<<PREP_TOTAL / 256, 256, 0, stream>>>(hw1, wco, wva, vw2, cw2, f1w, f2w, f3w, wp);
  k_init<<<VAR_BLOCKS + CON_BLOCKS, 256, 0, stream>>>(
      var_nf, con_nf, avar, acon, vw1, vb1, vb2, cw1, cb1, cb2, wp, xs, cnt);
  k_scatter<<<(NEDGE + 255) / 256, 256, 0, stream>>>(esrc, edst, etyp, cnt, slots);

  for (int l = 0; l < 4; ++l) {
    u16* xin  = xs + (size_t)l * NNODE * 64;
    u16* xout = xs + (size_t)(l + 1) * NNODE * 64;
    k_node<<<(NNODE + 127) / 128, 256, 0, stream>>>(
        xin, edge_f, wp + WP_NODE(l), hb1 + l * 64, hw2 + l * 64, hb2 + l, tbl);
    k_aggr<<<NNODE / 4, 256, 0, stream>>>(tbl, cnt, slots, bia + l * 64, xout);
  }

  k_head1<<<(NVAR + 127) / 128, 256, 0, stream>>>(xs, avar, wp, f1b, hAhi, hAlo);
  k_dense64<<<(NVAR + 127) / 128, 256, 0, stream>>>(hAhi, hAlo, wp + WP_FC2, f2b, hBhi, hBlo);
  k_dense64<<<(NVAR + 127) / 128, 256, 0, stream>>>(hBhi, hBlo, wp + WP_FC3, f3b, hAhi, hAlo);
  k_head4<<<(NVAR + 255) / 256, 256, 0, stream>>>(hAhi, hAlo, f4w, f4b, (float*)d_out);
}